// Round 2
// baseline (338.357 us; speedup 1.0000x reference)
//
#include <hip/hip_runtime.h>

#define T_MAX 50

#if __has_builtin(__builtin_amdgcn_exp2f)
#define EXP2F(x) __builtin_amdgcn_exp2f(x)
#else
#define EXP2F(x) exp2f(x)
#endif

// One block = one batch element. 256 threads, 4 consecutive pixels each
// (32x32 = 1024 pixels). Mask computed once per pixel, applied to 3 channels.
__global__ __launch_bounds__(256) void gm_mask_mul(
    const float* __restrict__ x0,
    const int*   __restrict__ t,
    const float* __restrict__ cx,
    const float* __restrict__ cy,
    float*       __restrict__ out)
{
    const int b   = blockIdx.x;
    const int tid = threadIdx.x;

    // scale[s] = -0.5*log2(e)/beta_s, beta_s = 1 + 0.1*s  (s = step-1)
    __shared__ float s_scale[T_MAX];
    if (tid < T_MAX) {
        const float beta = 1.0f + 0.1f * (float)tid;
        s_scale[tid] = (-0.5f * 1.44269504088896340736f) / beta;
    }

    const float fcx = cx[b];
    const float fcy = cy[b];
    const int   tb  = t[b];

    // Issue the x0 loads early so HBM latency hides under the mask loop.
    const float4* __restrict__ x4 = (const float4*)(x0 + (size_t)b * 3072);
    float4 v0 = x4[tid];
    float4 v1 = x4[256 + tid];
    float4 v2 = x4[512 + tid];

    __syncthreads();  // s_scale ready

    // Per-pixel squared distance. Pixel p: row = p>>5 (y), col = p&31 (x).
    // dx = col - cx, dy = row - cy  (matches meshgrid indexing="ij": xx=col, yy=row)
    const int p0 = tid * 4;
    float d2[4], m[4];
    #pragma unroll
    for (int k = 0; k < 4; ++k) {
        const int p = p0 + k;
        const float fx = (float)(p & 31) - fcx;
        const float fy = (float)(p >> 5) - fcy;
        d2[k] = fx * fx + fy * fy;
        m[k]  = 1.0f;
    }

    // mask = prod_{s=1..tb} (1 - exp2(d2 * scale_s)); block-uniform trip count.
    for (int s = 0; s < tb; ++s) {
        const float sc = s_scale[s];
        #pragma unroll
        for (int k = 0; k < 4; ++k) {
            const float g = EXP2F(d2[k] * sc);
            m[k] = __builtin_fmaf(-g, m[k], m[k]);  // m *= (1 - g)
        }
    }

    // Apply mask to all 3 channels, 16B coalesced stores.
    float4* __restrict__ o4 = (float4*)(out + (size_t)b * 3072);
    v0.x *= m[0]; v0.y *= m[1]; v0.z *= m[2]; v0.w *= m[3];
    v1.x *= m[0]; v1.y *= m[1]; v1.z *= m[2]; v1.w *= m[3];
    v2.x *= m[0]; v2.y *= m[1]; v2.z *= m[2]; v2.w *= m[3];
    o4[tid]       = v0;
    o4[256 + tid] = v1;
    o4[512 + tid] = v2;
}

extern "C" void kernel_launch(void* const* d_in, const int* in_sizes, int n_in,
                              void* d_out, int out_size, void* d_ws, size_t ws_size,
                              hipStream_t stream) {
    const float* x0 = (const float*)d_in[0];
    const int*   t  = (const int*)d_in[1];
    const float* cx = (const float*)d_in[2];
    const float* cy = (const float*)d_in[3];
    float* out = (float*)d_out;
    const int B = in_sizes[1];  // 16384

    gm_mask_mul<<<B, 256, 0, stream>>>(x0, t, cx, cy, out);
}